// Round 6
// baseline (129.492 us; speedup 1.0000x reference)
//
#include <hip/hip_runtime.h>
#include <math.h>

// Neural Additive Model: 256 per-feature MLPs 1->128->64->32->1 (ReLU), summed.
// B=8192, fp32 in/out.
//
// Exact rank-table decomposition: pre-relu h2[b,k] = x_b*Sw[r,k] + Sb[r,k],
// r = #(sorted layer-1 thresholds < x_b). Layer 3 on f16 MFMA 32x32x16
// (A=W3^T, B=h2), layer 4 reduced in-register + 1 shfl, 1 atomic/elem.
//
// Round 23: R22 counters finally exposed nam_fused (43-45us, FETCH 73 MB,
// 8M LDS conflict cycles, everything <35% busy -> latency-bound).
// (a) RESTORE xT transpose (R22's strided x = 9x overfetch: every 64B line
//     spans 16 features needed on all 8 XCDs -> 73 MB; proven -4-5us).
// (b) OCCUPANCY x2: grid 512 = (feature, batch-half), 8 rounds each ->
//     exactly 2 blocks/CU (LDS 2x53KB<160, 2048 thr, VGPR 52<=64) =
//     8 waves/SIMD for the latency-bound phase 2. Phase 1 duplicated per
//     feature (cheap, concurrent).
// (c) CONFLICT-FREE RANK WALK: the 4 LDS tree levels read skey[16m+7] etc
//     = stride-16 addresses on 2 banks (4-way structured conflict). Extract
//     levels into dense lv8[8]/lv4[16]/lv2[32]/lv1[64]: index rr>>4 etc ->
//     consecutive addresses -> distinct banks, zero conflicts.
// Table gather stays b64/stride-66 (random-r multinomial is at its floor).

#define NF   256
#define NH1  128
#define NH2  64
#define NH3  32
#define NB   8192

#define NRANK 129
#define ROWDW 66                      // dwords per table row (64 data + 2 pad)
#define ROWH  132                     // halfwords per row

typedef float    f32x16 __attribute__((ext_vector_type(16)));
typedef unsigned u32x4  __attribute__((ext_vector_type(4)));
typedef _Float16 h16x2  __attribute__((ext_vector_type(2)));
typedef _Float16 h16x8  __attribute__((ext_vector_type(8)));

// h2 pair: relu(x*Sw + Sb) on 2 packed f16 channels -> one B-frag dword
__device__ __forceinline__ unsigned pkh2(unsigned sw, unsigned sb, h16x2 xh) {
    h16x2 r = __builtin_elementwise_fma(xh, __builtin_bit_cast(h16x2, sw),
                                            __builtin_bit_cast(h16x2, sb));
    h16x2 hz = {(_Float16)0.f, (_Float16)0.f};
    return __builtin_bit_cast(unsigned, __builtin_elementwise_max(r, hz));
}

// ---------------- transpose: x[B][F] -> xT[F][B] in ws; fuses out-init ----------------
__global__ __launch_bounds__(1024) void transpose_x(
    const float* __restrict__ x, const float* __restrict__ bias,
    float* __restrict__ out, float* __restrict__ xt)
{
    __shared__ float xtile[64][65];        // padded -> conflict-free
    const int t = (int)threadIdx.x;
    const int T = blockIdx.x;              // 0..511
    const int bt = T >> 2, ft = T & 3;     // batch tile 0..127, feat tile 0..3

    if (T < 8) out[T * 1024 + t] = bias[0];   // out poisoned each launch

    #pragma unroll
    for (int it = 0; it < 4; ++it) {
        int idx = t + it * 1024;               // 4096 elems per tile
        int rr = idx >> 6, cc = idx & 63;      // read x[bt*64+rr][ft*64+cc]
        xtile[rr][cc] = x[(size_t)(bt * 64 + rr) * NF + ft * 64 + cc];
    }
    __syncthreads();
    #pragma unroll
    for (int it = 0; it < 4; ++it) {
        int idx = t + it * 1024;
        int cc = idx >> 6, rr = idx & 63;      // write xT[ft*64+cc][bt*64+rr]
        xt[(size_t)(ft * 64 + cc) * NB + bt * 64 + rr] = xtile[rr][cc];
    }
}

// ---------------- fused: one block (1024 thr) per (feature, batch-half) --------------
// Phase 1 builds the rank table in LDS (sort + chunked scan); phase 2 runs
// the MFMA batch loop (16 waves x 8 rounds x 512 batches) on the resident
// table. No table ever touches global memory. 2 blocks/CU.
__global__ __launch_bounds__(1024) void nam_fused(
    const float* __restrict__ W1, const float* __restrict__ b1,
    const float* __restrict__ W2, const float* __restrict__ b2,
    const float* __restrict__ W3, const float* __restrict__ b3,
    const float* __restrict__ W4, const float* __restrict__ b4,
    const float* __restrict__ xt,
    float* __restrict__ out)
{
    __shared__ unsigned SPD[NRANK * ROWDW];  // 33.3 KB packed f16 table
    __shared__ float rkey[NH1];              // raw thresholds
    __shared__ float skey[NH1];              // sorted thresholds
    __shared__ int   sidx[NH1];              // sorted payload (channel idx)
    __shared__ float w1s[NH1], b1s[NH1];
    __shared__ float Pbw[16][NH2], Pbb[16][NH2], Pdw[16][NH2], Pdb[16][NH2]; // 16 KB
    __shared__ float lv8[8], lv4[16], lv2[32], lv1[64];  // dense walk levels

    const int f = blockIdx.x >> 1;           // feature
    const int h = blockIdx.x & 1;            // batch half (4096 elems)
    const int t = (int)threadIdx.x;
    _Float16* SPh = (_Float16*)SPD;

    // ======== phase 1: build table (identical math to R21/R22) ========
    const float* __restrict__ gw2 = W2 + (size_t)f * NH1 * NH2;
    if (t < NH1) {
        float w  = W1[f * NH1 + t];
        float bb = b1[f * NH1 + t];
        w1s[t] = w; b1s[t] = bb;
        rkey[t] = (w != 0.0f) ? (-bb / w) : INFINITY;   // w==0: never toggled
    }
    __syncthreads();

    // counting-rank sort: 128 threads, each ranks its key vs all 128
    if (t < NH1) {
        const float my = rkey[t];
        int rk = 0;
        #pragma unroll 16
        for (int i = 0; i < NH1; ++i) {
            float ki = rkey[i];
            rk += (ki < my || (ki == my && i < t)) ? 1 : 0;
        }
        skey[rk] = my; sidx[rk] = t;
    }
    __syncthreads();

    // dense walk levels (conflict-free rankof): consecutive addrs -> banks
    if (t < 8)            lv8[t]      = skey[t * 16 + 7];
    else if (t < 24)      lv4[t - 8]  = skey[(t - 8) * 8 + 3];
    else if (t < 56)      lv2[t - 24] = skey[(t - 24) * 4 + 1];
    else if (t < 120)     lv1[t - 56] = skey[(t - 56) * 2];

    // chunked scan: 1024 threads = (k = t&63) x (chunk c = t>>6, 8 j/ranks each)
    {
        const int k = t & 63, c = t >> 6;
        float bw = 0.0f, bbp = 0.0f, dw = 0.0f, db = 0.0f;
        #pragma unroll
        for (int i = 0; i < 8; ++i) {
            int j = c * 8 + i;    // rank-0 base: w<0 active; w==0&&b>0 const-on
            float w = w1s[j], bv = b1s[j], w2v = gw2[j * NH2 + k];
            if (w < 0.0f) { bw = fmaf(w, w2v, bw); bbp = fmaf(bv, w2v, bbp); }
            else if (w == 0.0f && bv > 0.0f) { bbp = fmaf(bv, w2v, bbp); }
            int jj = sidx[c * 8 + i];   // toggle-delta partial
            float ww = w1s[jj], bv2 = b1s[jj], w2x = gw2[jj * NH2 + k];
            float s = (ww > 0.0f) ? 1.0f : ((ww < 0.0f) ? -1.0f : 0.0f);
            dw = fmaf(s * ww,  w2x, dw);
            db = fmaf(s * bv2, w2x, db);
        }
        Pbw[c][k] = bw; Pbb[c][k] = bbp; Pdw[c][k] = dw; Pdb[c][k] = db;
    }
    __syncthreads();
    {
        const int k = t & 63, c = t >> 6;
        float accw = 0.0f;
        float accb = b2[f * NH2 + k];    // b2 seed (round-8 lesson)
        #pragma unroll
        for (int c2 = 0; c2 < 16; ++c2) { accw += Pbw[c2][k]; accb += Pbb[c2][k]; }
        for (int c2 = 0; c2 < c; ++c2) { accw += Pdw[c2][k]; accb += Pdb[c2][k]; }
        // layout per row: Sw halves [0..63] (dwords 0..31), Sb halves
        // [64..127] (dwords 32..63), 2 pad dwords -> stride 66 dw
        if (c == 0) {
            SPh[k]      = (_Float16)accw;          // rank-0 row
            SPh[64 + k] = (_Float16)accb;
        }
        #pragma unroll
        for (int i = 0; i < 8; ++i) {
            int r = c * 8 + i;
            int j = sidx[r];                       // uniform per chunk -> broadcast
            float w = w1s[j], bv = b1s[j], w2v = gw2[j * NH2 + k];
            float s = (w > 0.0f) ? 1.0f : ((w < 0.0f) ? -1.0f : 0.0f);
            accw = fmaf(s * w,  w2v, accw);
            accb = fmaf(s * bv, w2v, accb);
            SPh[(r + 1) * ROWH + k]      = (_Float16)accw;
            SPh[(r + 1) * ROWH + 64 + k] = (_Float16)accb;
        }
    }
    __syncthreads();

    // ======== phase 2: MFMA batch loop on the resident table ========
    const int lane = t & 63, wv = t >> 6;   // 16 waves
    const int n = lane & 31, q2 = lane >> 5;

    // A-frags: A[m=lane&31][k=(lane>>5)*8+j] = W3[kk][ch=m]; 4 K-tiles of 16
    const float* __restrict__ w3g = W3 + f * NH2 * NH3;
    h16x8 A0, A1, A2, A3;
    #pragma unroll
    for (int j = 0; j < 8; ++j) {
        int kk = q2 * 8 + j;
        A0[j] = (_Float16)w3g[kk * NH3 + n];
        A1[j] = (_Float16)w3g[(kk + 16) * NH3 + n];
        A2[j] = (_Float16)w3g[(kk + 32) * NH3 + n];
        A3[j] = (_Float16)w3g[(kk + 48) * NH3 + n];
    }
    // per-lane channel constants for the 16 C/D rows:
    // row(reg) = (reg&3) + 8*(reg>>2) + 4*q2
    // bacc seeds the first MFMA's C operand directly (D!=C: no per-round movs)
    f32x16 bacc;
    float w4r[16];
    #pragma unroll
    for (int reg = 0; reg < 16; ++reg) {
        int row = (reg & 3) + 8 * (reg >> 2) + 4 * q2;
        bacc[reg] = b3[f * NH3 + row];
        w4r[reg]  = W4[f * NH3 + row];
    }
    const float b4f = b4[f];
    const float* __restrict__ xrow = xt + (size_t)f * NB;   // coalesced x
    // register-tree search levels s=64/32/16 (7 thresholds)
    const float t63 = skey[63], t31 = skey[31], t95 = skey[95];
    const float t15 = skey[15], t47 = skey[47], t79 = skey[79], t111 = skey[111];

    // rank = #(skey < q): 3 register levels + 4 conflict-free LDS levels
    auto rankof = [&](float q) -> int {
        int rr = (t63 < q) ? 64 : 0;
        {
            float l1 = (rr & 64) ? t95 : t31;
            if (l1 < q) rr += 32;
            float m0 = (rr & 64) ? t79  : t15;
            float m1 = (rr & 64) ? t111 : t47;
            float l2 = (rr & 32) ? m1 : m0;
            if (l2 < q) rr += 16;
        }
        if (lv8[rr >> 4] < q) rr += 8;
        if (lv4[rr >> 3] < q) rr += 4;
        if (lv2[rr >> 2] < q) rr += 2;
        if (lv1[rr >> 1] < q) rr += 1;
        return rr;
    };

    // 8 rounds x 512 batches over this block's half; round order rotated by
    // f so features don't hit the same out[] lines in lockstep. Software-
    // pipelined x/rank (coalesced xrow reads, 2 lines/wave).
    auto bat = [&](int round) -> int {
        return h * 4096 + (((round + f) & 7) * 16 + wv) * 32 + n;
    };
    float xv = xrow[bat(0)];
    int r = rankof(xv);

    #pragma unroll 1
    for (int round = 0; round < 8; ++round) {
        const int base = h * 4096 + (((round + f) & 7) * 16 + wv) * 32;
        // next round's x (last-round prefetch wraps to round 0's slot; unused)
        const float xnext = xrow[bat((round + 1) & 7)];

        // gather lane's dword pairs for its column n, row r, as 16x
        // ds_read_b64: dw addr = r*66 + {Sw: 8T+4q2, +2 | Sb: +32}.
        const int rb = r * ROWDW + 4 * q2;
        uint2 SW0a = *(const uint2*)&SPD[rb +  0], SW0b = *(const uint2*)&SPD[rb +  2];
        uint2 SW1a = *(const uint2*)&SPD[rb +  8], SW1b = *(const uint2*)&SPD[rb + 10];
        uint2 SW2a = *(const uint2*)&SPD[rb + 16], SW2b = *(const uint2*)&SPD[rb + 18];
        uint2 SW3a = *(const uint2*)&SPD[rb + 24], SW3b = *(const uint2*)&SPD[rb + 26];
        uint2 SB0a = *(const uint2*)&SPD[rb + 32], SB0b = *(const uint2*)&SPD[rb + 34];
        uint2 SB1a = *(const uint2*)&SPD[rb + 40], SB1b = *(const uint2*)&SPD[rb + 42];
        uint2 SB2a = *(const uint2*)&SPD[rb + 48], SB2b = *(const uint2*)&SPD[rb + 50];
        uint2 SB3a = *(const uint2*)&SPD[rb + 56], SB3b = *(const uint2*)&SPD[rb + 58];

        // B-frags: one pk_fma + pk_max per 2 channels
        const h16x2 xh = {(_Float16)xv, (_Float16)xv};
        u32x4 d0, d1, d2, d3;
        d0.x = pkh2(SW0a.x, SB0a.x, xh); d0.y = pkh2(SW0a.y, SB0a.y, xh);
        d0.z = pkh2(SW0b.x, SB0b.x, xh); d0.w = pkh2(SW0b.y, SB0b.y, xh);
        d1.x = pkh2(SW1a.x, SB1a.x, xh); d1.y = pkh2(SW1a.y, SB1a.y, xh);
        d1.z = pkh2(SW1b.x, SB1b.x, xh); d1.w = pkh2(SW1b.y, SB1b.y, xh);
        d2.x = pkh2(SW2a.x, SB2a.x, xh); d2.y = pkh2(SW2a.y, SB2a.y, xh);
        d2.z = pkh2(SW2b.x, SB2b.x, xh); d2.w = pkh2(SW2b.y, SB2b.y, xh);
        d3.x = pkh2(SW3a.x, SB3a.x, xh); d3.y = pkh2(SW3a.y, SB3a.y, xh);
        d3.z = pkh2(SW3b.x, SB3b.x, xh); d3.w = pkh2(SW3b.y, SB3b.y, xh);
        h16x8 B0 = __builtin_bit_cast(h16x8, d0);
        h16x8 B1 = __builtin_bit_cast(h16x8, d1);
        h16x8 B2 = __builtin_bit_cast(h16x8, d2);
        h16x8 B3 = __builtin_bit_cast(h16x8, d3);

        // layer 3: D[ch][batch], fp32 acc seeded with b3 rows via C operand
        f32x16 acc = __builtin_amdgcn_mfma_f32_32x32x16_f16(A0, B0, bacc, 0, 0, 0);
        acc = __builtin_amdgcn_mfma_f32_32x32x16_f16(A1, B1, acc, 0, 0, 0);
        acc = __builtin_amdgcn_mfma_f32_32x32x16_f16(A2, B2, acc, 0, 0, 0);
        acc = __builtin_amdgcn_mfma_f32_32x32x16_f16(A3, B3, acc, 0, 0, 0);

        // next round's rank walk (LDS pipe) in the shadow of MFMA + reduce
        const int rnext = rankof(xnext);

        // layer 4: reduce lane's own 16 channel rows, 1 shfl over q2, 1 atomic
        float p = 0.0f;
        #pragma unroll
        for (int reg = 0; reg < 16; ++reg)
            p = fmaf(fmaxf(acc[reg], 0.0f), w4r[reg], p);
        p += __shfl_xor(p, 32);
        if (lane < 32) atomicAdd(&out[base + lane], p + b4f);

        xv = xnext; r = rnext;
    }
}

extern "C" void kernel_launch(void* const* d_in, const int* in_sizes, int n_in,
                              void* d_out, int out_size, void* d_ws, size_t ws_size,
                              hipStream_t stream) {
    const float* x    = (const float*)d_in[0];
    const float* W1   = (const float*)d_in[1];
    const float* b1   = (const float*)d_in[2];
    const float* W2   = (const float*)d_in[3];
    const float* b2   = (const float*)d_in[4];
    const float* W3   = (const float*)d_in[5];
    const float* b3   = (const float*)d_in[6];
    const float* W4   = (const float*)d_in[7];
    const float* b4   = (const float*)d_in[8];
    const float* bias = (const float*)d_in[9];
    float* out   = (float*)d_out;
    float* xtw   = (float*)d_ws;      // ws holds xT: 8 MB

    // transpose (both sides coalesced) + out-init
    transpose_x<<<512, 1024, 0, stream>>>(x, bias, out, xtw);
    // fused: grid 512 = (feature, half) -> 2 blocks/CU, 8 waves/SIMD
    nam_fused<<<NF * 2, 1024, 0, stream>>>(W1, b1, W2, b2, W3, b3, W4, b4,
                                           xtw, out);
}

// Round 8
// 112.248 us; speedup vs baseline: 1.1536x; 1.1536x over previous
//
#include <hip/hip_runtime.h>
#include <math.h>

// Neural Additive Model: 256 per-feature MLPs 1->128->64->32->1 (ReLU), summed.
// B=8192, fp32 in/out.
//
// Exact rank-table decomposition: pre-relu h2[b,k] = x_b*Sw[r,k] + Sb[r,k],
// r = #(sorted layer-1 thresholds < x_b). Layer 3 on f16 MFMA 32x32x16
// (A=W3^T, B=h2), layer 4 reduced in-register + 1 shfl, 1 atomic/elem.
//
// Round 25: REVERT to R21 (proven best, 111.7us) + R23's dense walk levels.
// R24's hipLaunchCooperativeKernel broke the harness (graph capture) -> DNF.
// R23 taught: phase 2 is LDS/VALU-throughput-bound, NOT occupancy-bound
// (35% occupancy at both 1 and 2 blocks/CU); duplicating phase 1 is loss.
// R22 taught: strided x = 9x overfetch (73 MB), b64 gather no better than
// b128. So: R21's two-kernel structure verbatim (transpose_x fusing
// out-init; nam_fused 1 block/feature, 16 rounds, 17-uint4 table, b128
// gather) with ONE validated addition: dense rank-walk levels lv8/lv4/lv2/
// lv1 (R23 measured conflicts 8.0M -> 6.8M; the walk's skey[16m+7] reads
// were stride-16 = 2 banks = 4-way structured conflict; dense arrays give
// consecutive addrs -> conflict-free).

#define NF   256
#define NH1  128
#define NH2  64
#define NH3  32
#define NB   8192

#define NRANK 129
#define ROW4  17                      // uint4 per table row (16 data + 1 pad)
#define ROWH  136                     // halfwords per row

typedef float    f32x16 __attribute__((ext_vector_type(16)));
typedef unsigned u32x4  __attribute__((ext_vector_type(4)));
typedef _Float16 h16x2  __attribute__((ext_vector_type(2)));
typedef _Float16 h16x8  __attribute__((ext_vector_type(8)));

// h2 pair: relu(x*Sw + Sb) on 2 packed f16 channels -> one B-frag dword
__device__ __forceinline__ unsigned pkh2(unsigned sw, unsigned sb, h16x2 xh) {
    h16x2 r = __builtin_elementwise_fma(xh, __builtin_bit_cast(h16x2, sw),
                                            __builtin_bit_cast(h16x2, sb));
    h16x2 hz = {(_Float16)0.f, (_Float16)0.f};
    return __builtin_bit_cast(unsigned, __builtin_elementwise_max(r, hz));
}

// ---------------- transpose: x[B][F] -> xT[F][B] in ws; fuses out-init ----------------
__global__ __launch_bounds__(1024) void transpose_x(
    const float* __restrict__ x, const float* __restrict__ bias,
    float* __restrict__ out, float* __restrict__ xt)
{
    __shared__ float xtile[64][65];        // padded -> conflict-free
    const int t = (int)threadIdx.x;
    const int T = blockIdx.x;              // 0..511
    const int bt = T >> 2, ft = T & 3;     // batch tile 0..127, feat tile 0..3

    if (T < 8) out[T * 1024 + t] = bias[0];   // out poisoned each launch

    #pragma unroll
    for (int it = 0; it < 4; ++it) {
        int idx = t + it * 1024;               // 4096 elems per tile
        int rr = idx >> 6, cc = idx & 63;      // read x[bt*64+rr][ft*64+cc]
        xtile[rr][cc] = x[(size_t)(bt * 64 + rr) * NF + ft * 64 + cc];
    }
    __syncthreads();
    #pragma unroll
    for (int it = 0; it < 4; ++it) {
        int idx = t + it * 1024;
        int cc = idx >> 6, rr = idx & 63;      // write xT[ft*64+cc][bt*64+rr]
        xt[(size_t)(ft * 64 + cc) * NB + bt * 64 + rr] = xtile[rr][cc];
    }
}

// ---------------- fused: one block (1024 thr) per feature ----------------
// Phase 1 builds the rank table in LDS (sort + chunked scan); phase 2 runs
// the MFMA batch loop (16 waves x 16 rounds x 512 batches) on the resident
// table. No table ever touches global memory.
__global__ __launch_bounds__(1024) void nam_fused(
    const float* __restrict__ W1, const float* __restrict__ b1,
    const float* __restrict__ W2, const float* __restrict__ b2,
    const float* __restrict__ W3, const float* __restrict__ b3,
    const float* __restrict__ W4, const float* __restrict__ b4,
    const float* __restrict__ xt,
    float* __restrict__ out)
{
    __shared__ u32x4 SP4[NRANK * ROW4];    // 35.1 KB packed f16 table
    __shared__ float rkey[NH1];            // raw thresholds
    __shared__ float skey[NH1];            // sorted thresholds
    __shared__ int   sidx[NH1];            // sorted payload (channel idx)
    __shared__ float w1s[NH1], b1s[NH1];
    __shared__ float Pbw[16][NH2], Pbb[16][NH2], Pdw[16][NH2], Pdb[16][NH2]; // 16 KB
    __shared__ float lv8[8], lv4[16], lv2[32], lv1[64];  // dense walk levels

    const int f = blockIdx.x;
    const int t = (int)threadIdx.x;
    _Float16* SPh = (_Float16*)SP4;

    // ======== phase 1: build table (R21-proven math) ========
    const float* __restrict__ gw2 = W2 + (size_t)f * NH1 * NH2;
    if (t < NH1) {
        float w  = W1[f * NH1 + t];
        float bb = b1[f * NH1 + t];
        w1s[t] = w; b1s[t] = bb;
        rkey[t] = (w != 0.0f) ? (-bb / w) : INFINITY;   // w==0: never toggled
    }
    __syncthreads();

    // counting-rank sort: 128 threads, each ranks its key vs all 128
    if (t < NH1) {
        const float my = rkey[t];
        int rk = 0;
        #pragma unroll 16
        for (int i = 0; i < NH1; ++i) {
            float ki = rkey[i];
            rk += (ki < my || (ki == my && i < t)) ? 1 : 0;
        }
        skey[rk] = my; sidx[rk] = t;
    }
    __syncthreads();

    // dense walk levels (conflict-free rankof): consecutive addrs -> banks
    if (t < 8)            lv8[t]      = skey[t * 16 + 7];
    else if (t < 24)      lv4[t - 8]  = skey[(t - 8) * 8 + 3];
    else if (t < 56)      lv2[t - 24] = skey[(t - 24) * 4 + 1];
    else if (t < 120)     lv1[t - 56] = skey[(t - 56) * 2];

    // chunked scan: 1024 threads = (k = t&63) x (chunk c = t>>6, 8 j/ranks each)
    {
        const int k = t & 63, c = t >> 6;
        float bw = 0.0f, bbp = 0.0f, dw = 0.0f, db = 0.0f;
        #pragma unroll
        for (int i = 0; i < 8; ++i) {
            int j = c * 8 + i;    // rank-0 base: w<0 active; w==0&&b>0 const-on
            float w = w1s[j], bv = b1s[j], w2v = gw2[j * NH2 + k];
            if (w < 0.0f) { bw = fmaf(w, w2v, bw); bbp = fmaf(bv, w2v, bbp); }
            else if (w == 0.0f && bv > 0.0f) { bbp = fmaf(bv, w2v, bbp); }
            int jj = sidx[c * 8 + i];   // toggle-delta partial
            float ww = w1s[jj], bv2 = b1s[jj], w2x = gw2[jj * NH2 + k];
            float s = (ww > 0.0f) ? 1.0f : ((ww < 0.0f) ? -1.0f : 0.0f);
            dw = fmaf(s * ww,  w2x, dw);
            db = fmaf(s * bv2, w2x, db);
        }
        Pbw[c][k] = bw; Pbb[c][k] = bbp; Pdw[c][k] = dw; Pdb[c][k] = db;
    }
    __syncthreads();
    {
        const int k = t & 63, c = t >> 6;
        float accw = 0.0f;
        float accb = b2[f * NH2 + k];    // b2 seed (round-8 lesson)
        #pragma unroll
        for (int c2 = 0; c2 < 16; ++c2) { accw += Pbw[c2][k]; accb += Pbb[c2][k]; }
        for (int c2 = 0; c2 < c; ++c2) { accw += Pdw[c2][k]; accb += Pdb[c2][k]; }
        // layout per row: Sw halves [0..63], Sb halves [64..127], pad to 136
        if (c == 0) {
            SPh[k]      = (_Float16)accw;          // rank-0 row
            SPh[64 + k] = (_Float16)accb;
        }
        #pragma unroll
        for (int i = 0; i < 8; ++i) {
            int r = c * 8 + i;
            int j = sidx[r];                       // uniform per chunk -> broadcast
            float w = w1s[j], bv = b1s[j], w2v = gw2[j * NH2 + k];
            float s = (w > 0.0f) ? 1.0f : ((w < 0.0f) ? -1.0f : 0.0f);
            accw = fmaf(s * w,  w2v, accw);
            accb = fmaf(s * bv, w2v, accb);
            SPh[(r + 1) * ROWH + k]      = (_Float16)accw;
            SPh[(r + 1) * ROWH + 64 + k] = (_Float16)accb;
        }
    }
    __syncthreads();

    // ======== phase 2: MFMA batch loop on the resident table ========
    const int lane = t & 63, wv = t >> 6;   // 16 waves
    const int n = lane & 31, q2 = lane >> 5;

    // A-frags: A[m=lane&31][k=(lane>>5)*8+j] = W3[kk][ch=m]; 4 K-tiles of 16
    const float* __restrict__ w3g = W3 + f * NH2 * NH3;
    h16x8 A0, A1, A2, A3;
    #pragma unroll
    for (int j = 0; j < 8; ++j) {
        int kk = q2 * 8 + j;
        A0[j] = (_Float16)w3g[kk * NH3 + n];
        A1[j] = (_Float16)w3g[(kk + 16) * NH3 + n];
        A2[j] = (_Float16)w3g[(kk + 32) * NH3 + n];
        A3[j] = (_Float16)w3g[(kk + 48) * NH3 + n];
    }
    // per-lane channel constants for the 16 C/D rows:
    // row(reg) = (reg&3) + 8*(reg>>2) + 4*q2
    // bacc seeds the first MFMA's C operand directly (D!=C: no per-round movs)
    f32x16 bacc;
    float w4r[16];
    #pragma unroll
    for (int reg = 0; reg < 16; ++reg) {
        int row = (reg & 3) + 8 * (reg >> 2) + 4 * q2;
        bacc[reg] = b3[f * NH3 + row];
        w4r[reg]  = W4[f * NH3 + row];
    }
    const float b4f = b4[f];
    const float* __restrict__ xrow = xt + (size_t)f * NB;   // coalesced x
    // register-tree search levels s=64/32/16 (7 thresholds)
    const float t63 = skey[63], t31 = skey[31], t95 = skey[95];
    const float t15 = skey[15], t47 = skey[47], t79 = skey[79], t111 = skey[111];

    // rank = #(skey < q): 3 register levels + 4 conflict-free LDS levels
    auto rankof = [&](float q) -> int {
        int rr = (t63 < q) ? 64 : 0;
        {
            float l1 = (rr & 64) ? t95 : t31;
            if (l1 < q) rr += 32;
            float m0 = (rr & 64) ? t79  : t15;
            float m1 = (rr & 64) ? t111 : t47;
            float l2 = (rr & 32) ? m1 : m0;
            if (l2 < q) rr += 16;
        }
        if (lv8[rr >> 4] < q) rr += 8;
        if (lv4[rr >> 3] < q) rr += 4;
        if (lv2[rr >> 2] < q) rr += 2;
        if (lv1[rr >> 1] < q) rr += 1;
        return rr;
    };

    // 16 rounds x 512 batches; round order rotated by f so features don't
    // hit the same out[] lines in lockstep. Software-pipelined x/rank.
    auto bat = [&](int round) -> int {
        return (((round + f) & 15) * 16 + wv) * 32 + n;
    };
    float xv = xrow[bat(0)];
    int r = rankof(xv);

    #pragma unroll 1
    for (int round = 0; round < 16; ++round) {
        const int base = (((round + f) & 15) * 16 + wv) * 32;
        // next round's x (last-round prefetch wraps to round 0's slot; unused)
        const float xnext = xrow[bat((round + 1) & 15)];

        // gather lane's pair-dwords for its column n, row r:
        // Sw uint4 tiles T*2+q2 (T=0..3), Sb at +8
        const int ro = r * ROW4;
        u32x4 SW0 = SP4[ro + q2],      SW1 = SP4[ro + 2 + q2];
        u32x4 SW2 = SP4[ro + 4 + q2],  SW3 = SP4[ro + 6 + q2];
        u32x4 SB0 = SP4[ro + 8 + q2],  SB1 = SP4[ro + 10 + q2];
        u32x4 SB2 = SP4[ro + 12 + q2], SB3 = SP4[ro + 14 + q2];

        // B-frags: one pk_fma + pk_max per 2 channels
        const h16x2 xh = {(_Float16)xv, (_Float16)xv};
        u32x4 d0, d1, d2, d3;
        d0.x = pkh2(SW0.x, SB0.x, xh); d0.y = pkh2(SW0.y, SB0.y, xh);
        d0.z = pkh2(SW0.z, SB0.z, xh); d0.w = pkh2(SW0.w, SB0.w, xh);
        d1.x = pkh2(SW1.x, SB1.x, xh); d1.y = pkh2(SW1.y, SB1.y, xh);
        d1.z = pkh2(SW1.z, SB1.z, xh); d1.w = pkh2(SW1.w, SB1.w, xh);
        d2.x = pkh2(SW2.x, SB2.x, xh); d2.y = pkh2(SW2.y, SB2.y, xh);
        d2.z = pkh2(SW2.z, SB2.z, xh); d2.w = pkh2(SW2.w, SB2.w, xh);
        d3.x = pkh2(SW3.x, SB3.x, xh); d3.y = pkh2(SW3.y, SB3.y, xh);
        d3.z = pkh2(SW3.z, SB3.z, xh); d3.w = pkh2(SW3.w, SB3.w, xh);
        h16x8 B0 = __builtin_bit_cast(h16x8, d0);
        h16x8 B1 = __builtin_bit_cast(h16x8, d1);
        h16x8 B2 = __builtin_bit_cast(h16x8, d2);
        h16x8 B3 = __builtin_bit_cast(h16x8, d3);

        // layer 3: D[ch][batch], fp32 acc seeded with b3 rows via C operand
        f32x16 acc = __builtin_amdgcn_mfma_f32_32x32x16_f16(A0, B0, bacc, 0, 0, 0);
        acc = __builtin_amdgcn_mfma_f32_32x32x16_f16(A1, B1, acc, 0, 0, 0);
        acc = __builtin_amdgcn_mfma_f32_32x32x16_f16(A2, B2, acc, 0, 0, 0);
        acc = __builtin_amdgcn_mfma_f32_32x32x16_f16(A3, B3, acc, 0, 0, 0);

        // next round's rank walk (LDS pipe) in the shadow of MFMA + reduce
        const int rnext = rankof(xnext);

        // layer 4: reduce lane's own 16 channel rows, 1 shfl over q2, 1 atomic
        float p = 0.0f;
        #pragma unroll
        for (int reg = 0; reg < 16; ++reg)
            p = fmaf(fmaxf(acc[reg], 0.0f), w4r[reg], p);
        p += __shfl_xor(p, 32);
        if (lane < 32) atomicAdd(&out[base + lane], p + b4f);

        xv = xnext; r = rnext;
    }
}

extern "C" void kernel_launch(void* const* d_in, const int* in_sizes, int n_in,
                              void* d_out, int out_size, void* d_ws, size_t ws_size,
                              hipStream_t stream) {
    const float* x    = (const float*)d_in[0];
    const float* W1   = (const float*)d_in[1];
    const float* b1   = (const float*)d_in[2];
    const float* W2   = (const float*)d_in[3];
    const float* b2   = (const float*)d_in[4];
    const float* W3   = (const float*)d_in[5];
    const float* b3   = (const float*)d_in[6];
    const float* W4   = (const float*)d_in[7];
    const float* b4   = (const float*)d_in[8];
    const float* bias = (const float*)d_in[9];
    float* out   = (float*)d_out;
    float* xtw   = (float*)d_ws;      // ws holds xT: 8 MB

    // transpose (both sides coalesced) + out-init
    transpose_x<<<512, 1024, 0, stream>>>(x, bias, out, xtw);
    // fused: 1 block/feature = 1 block/CU; table lives and dies in LDS
    nam_fused<<<NF, 1024, 0, stream>>>(W1, b1, W2, b2, W3, b3, W4, b4,
                                       xtw, out);
}